// Round 1
// baseline (446.372 us; speedup 1.0000x reference)
//
#include <hip/hip_runtime.h>
#include <stdint.h>
#include <math.h>

#define B 4096
#define D 512
// N_IMG fixed at 8 by the reference's setup_inputs()
#define NIMG_SHIFT 3

// RNG variant: 1 = jax_threefry_partitionable (default in modern JAX), 0 = original
#define RNG_PARTITIONABLE 1

#define RT 32          // rows per neg-block
#define CCHUNK 1024    // cols per chunk
#define NCHUNK (B / CCHUNK)
#define TC 128         // cols per tile
#define KC 32
#define LP 36          // padded LDS row stride (floats), 16B-aligned, odd multiple of 16B

__host__ __device__ inline void tf2x32(uint32_t k0, uint32_t k1,
                                       uint32_t x0, uint32_t x1,
                                       uint32_t& y0, uint32_t& y1) {
  const uint32_t ks2 = k0 ^ k1 ^ 0x1BD11BDAu;
  uint32_t v0 = x0 + k0, v1 = x1 + k1;
#define RR(r) { v0 += v1; v1 = (v1 << (r)) | (v1 >> (32 - (r))); v1 ^= v0; }
  RR(13) RR(15) RR(26) RR(6)   v0 += k1;  v1 += ks2 + 1u;
  RR(17) RR(29) RR(16) RR(24)  v0 += ks2; v1 += k0 + 2u;
  RR(13) RR(15) RR(26) RR(6)   v0 += k0;  v1 += k1 + 3u;
  RR(17) RR(29) RR(16) RR(24)  v0 += k1;  v1 += ks2 + 4u;
  RR(13) RR(15) RR(26) RR(6)   v0 += ks2; v1 += k0 + 5u;
#undef RR
  y0 = v0; y1 = v1;
}

// 32-bit random draw at flat index i for a given key (partitionable mapping)
__device__ inline uint32_t draw_bits(uint32_t key0, uint32_t key1, uint32_t flat) {
#if RNG_PARTITIONABLE
  uint32_t y0, y1;
  tf2x32(key0, key1, 0u, flat, y0, y1);
  return y1;   // bits2 (lo word) for bit_width==32
#else
  // original: counts iota(16M) split in halves
  const uint32_t H = (uint32_t)(B) * (uint32_t)(B) / 2u;
  uint32_t y0, y1;
  if (flat < H) { tf2x32(key0, key1, flat, flat + H, y0, y1); return y0; }
  else          { tf2x32(key0, key1, flat - H, flat, y0, y1); return y1; }
#endif
}

__device__ inline float gumbel_from_bits(uint32_t bits) {
  float f = __uint_as_float((bits >> 9) | 0x3f800000u) - 1.0f;
  float u = (f == 0.0f) ? 1.17549435e-38f : f;
  return -logf(-logf(u));
}

// ---------------- Kernel 1: row sum-of-squares for Q and G ----------------
__global__ __launch_bounds__(256) void norms_k(const float* __restrict__ Q,
                                               const float* __restrict__ G,
                                               float* __restrict__ nq,
                                               float* __restrict__ ng) {
  int gtid = blockIdx.x * blockDim.x + threadIdx.x;
  int wave = gtid >> 6;
  int lane = gtid & 63;
  if (wave >= 2 * B) return;
  const float* src = (wave < B) ? Q : G;
  int row = (wave < B) ? wave : (wave - B);
  const float4* p = (const float4*)(src + (size_t)row * D);
  float s = 0.0f;
#pragma unroll
  for (int i = 0; i < 2; i++) {
    float4 v = p[lane + 64 * i];
    s += v.x * v.x + v.y * v.y + v.z * v.z + v.w * v.w;
  }
#pragma unroll
  for (int off = 32; off; off >>= 1) s += __shfl_xor(s, off, 64);
  if (lane == 0) { if (wave < B) nq[row] = s; else ng[row] = s; }
}

// ---------------- Kernel 2: positive categorical sampling ----------------
__global__ __launch_bounds__(256) void pos_k(const float* __restrict__ Q,
                                             const float* __restrict__ G,
                                             const float* __restrict__ nq,
                                             const float* __restrict__ ng,
                                             float* __restrict__ pscore,
                                             float* __restrict__ spos,
                                             uint32_t kp0, uint32_t kp1) {
  __shared__ float Qs[8][D];
  __shared__ float Gs[8][D];
  __shared__ float dots[8][8];
  int t = threadIdx.x;
  int rbase = blockIdx.x * 8;
#pragma unroll
  for (int s = 0; s < 4; s++) {
    int idx = t + 256 * s;        // 0..1023, 128 float4 per row
    int rr = idx >> 7;
    int kk = idx & 127;
    ((float4*)&Qs[rr][0])[kk] = ((const float4*)(Q + (size_t)(rbase + rr) * D))[kk];
    ((float4*)&Gs[rr][0])[kk] = ((const float4*)(G + (size_t)(rbase + rr) * D))[kk];
  }
  __syncthreads();
  {
    int p = t >> 2;               // dot id 0..63
    int part = t & 3;             // 4-way K split
    int i = p >> 3, j = p & 7;
    float s = 0.0f;
    int k0 = part * 128;
    for (int k = k0; k < k0 + 128; k++) s += Qs[i][k] * Gs[j][k];
    s += __shfl_xor(s, 1, 64);
    s += __shfl_xor(s, 2, 64);
    if (part == 0) dots[i][j] = s;
  }
  __syncthreads();
  if (t < 8) {
    int i = t;
    int r = rbase + i;
    float nqr = nq[r];
    float best = -INFINITY;
    float bdp = 0.0f;
#pragma unroll
    for (int j = 0; j < 8; j++) {
      if (j == i) continue;
      int c = rbase + j;
      float dp = fmaxf(nqr + ng[c] - 2.0f * dots[i][j], 1e-8f);
      uint32_t bits = draw_bits(kp0, kp1, (uint32_t)(r * B + c));
      float logit = logf(dp) + gumbel_from_bits(bits);
      if (logit > best) { best = logit; bdp = dp; }
    }
    pscore[r] = bdp;
    spos[r] = sqrtf(bdp);
  }
}

// ---------------- Kernel 3: fused GEMM + neg-row reductions ----------------
__global__ __launch_bounds__(256) void neg_k(const float* __restrict__ Q,
                                             const float* __restrict__ G,
                                             const float* __restrict__ nq,
                                             const float* __restrict__ ng,
                                             const float* __restrict__ pscore,
                                             uint32_t kn0, uint32_t kn1,
                                             uint32_t* __restrict__ bestKey,
                                             uint32_t* __restrict__ bestC,
                                             float* __restrict__ bestDn,
                                             float* __restrict__ minDn,
                                             uint32_t* __restrict__ minC) {
  __shared__ float Qs[RT][LP];
  __shared__ float Gs[TC][LP];
  int t = threadIdx.x;
  int ty = t >> 5, tx = t & 31;
  int r0 = blockIdx.y * RT;
  int chunk = blockIdx.x;
  int c0chunk = chunk * CCHUNK;

  float nqv[4], thrv[4];
  int rg[4];
#pragma unroll
  for (int i = 0; i < 4; i++) {
    int r = r0 + ty + 8 * i;
    nqv[i] = nq[r];
    thrv[i] = pscore[r] + 1e-4f;
    rg[i] = r >> NIMG_SHIFT;
  }

  uint32_t bKey[4], bC[4], mC[4];
  float bD[4], mD[4];
#pragma unroll
  for (int i = 0; i < 4; i++) {
    bKey[i] = 0u; bC[i] = 0xFFFFFFFFu; bD[i] = 0.0f;
    mD[i] = INFINITY; mC[i] = 0xFFFFFFFFu;
  }

#pragma unroll 1
  for (int tt = 0; tt < CCHUNK / TC; tt++) {
    int c0 = c0chunk + tt * TC;
    float acc[4][4];
#pragma unroll
    for (int i = 0; i < 4; i++)
#pragma unroll
      for (int j = 0; j < 4; j++) acc[i][j] = 0.0f;

#pragma unroll 1
    for (int kk = 0; kk < D; kk += KC) {
      __syncthreads();
      {
        int rr = t >> 3, qq = t & 7;   // 32 rows x 8 quads
        float4 v = *(const float4*)(Q + (size_t)(r0 + rr) * D + kk + 4 * qq);
        *(float4*)(&Qs[rr][4 * qq]) = v;
      }
#pragma unroll
      for (int s = 0; s < 4; s++) {
        int idx = t + 256 * s;         // 128 rows x 8 quads
        int cc = idx >> 3, qq = idx & 7;
        float4 v = *(const float4*)(G + (size_t)(c0 + cc) * D + kk + 4 * qq);
        *(float4*)(&Gs[cc][4 * qq]) = v;
      }
      __syncthreads();
#pragma unroll
      for (int q = 0; q < 8; q++) {
        float4 qa[4], gb[4];
#pragma unroll
        for (int i = 0; i < 4; i++) qa[i] = *(const float4*)(&Qs[ty + 8 * i][4 * q]);
#pragma unroll
        for (int j = 0; j < 4; j++) gb[j] = *(const float4*)(&Gs[tx + 32 * j][4 * q]);
#pragma unroll
        for (int i = 0; i < 4; i++)
#pragma unroll
          for (int j = 0; j < 4; j++) {
            acc[i][j] = fmaf(qa[i].x, gb[j].x, acc[i][j]);
            acc[i][j] = fmaf(qa[i].y, gb[j].y, acc[i][j]);
            acc[i][j] = fmaf(qa[i].z, gb[j].z, acc[i][j]);
            acc[i][j] = fmaf(qa[i].w, gb[j].w, acc[i][j]);
          }
      }
    }
    // epilogue: distance + reductions (per-thread columns ascend with j and tt)
#pragma unroll
    for (int j = 0; j < 4; j++) {
      int c = c0 + tx + 32 * j;
      float ngv = ng[c];
      int cg = c >> NIMG_SHIFT;
#pragma unroll
      for (int i = 0; i < 4; i++) {
        float d = fmaxf(nqv[i] + ngv - 2.0f * acc[i][j], 1e-8f);
        float dn = (cg == rg[i]) ? 1e25f : d;
        if (dn < mD[i]) { mD[i] = dn; mC[i] = (uint32_t)c; }
        if (dn < thrv[i]) {
          int r = r0 + ty + 8 * i;
          uint32_t bits = draw_bits(kn0, kn1, (uint32_t)(r * B + c));
          uint32_t key = (bits >> 9) + 1u;   // monotone in gumbel; +1 so 0 == "none"
          if (key > bKey[i]) { bKey[i] = key; bC[i] = (uint32_t)c; bD[i] = dn; }
        }
      }
    }
  }

  // cross-lane reduce over the 32 tx lanes (same ty half-wave), index-aware ties
#pragma unroll
  for (int i = 0; i < 4; i++) {
#pragma unroll
    for (int off = 16; off >= 1; off >>= 1) {
      uint32_t kO = __shfl_xor(bKey[i], off, 64);
      uint32_t cO = __shfl_xor(bC[i], off, 64);
      float dO = __shfl_xor(bD[i], off, 64);
      if (kO > bKey[i] || (kO == bKey[i] && cO < bC[i])) { bKey[i] = kO; bC[i] = cO; bD[i] = dO; }
      float mdO = __shfl_xor(mD[i], off, 64);
      uint32_t mcO = __shfl_xor(mC[i], off, 64);
      if (mdO < mD[i] || (mdO == mD[i] && mcO < mC[i])) { mD[i] = mdO; mC[i] = mcO; }
    }
    if (tx == 0) {
      int r = r0 + ty + 8 * i;
      int p = r * NCHUNK + chunk;
      bestKey[p] = bKey[i]; bestC[p] = bC[i]; bestDn[p] = bD[i];
      minDn[p] = mD[i]; minC[p] = mC[i];
    }
  }
}

// ---------------- Kernel 4: combine chunks, softplus, mean ----------------
__global__ __launch_bounds__(256) void fin_k(const float* __restrict__ spos,
                                             const uint32_t* __restrict__ bestKey,
                                             const uint32_t* __restrict__ bestC,
                                             const float* __restrict__ bestDn,
                                             const float* __restrict__ minDn,
                                             const uint32_t* __restrict__ minC,
                                             float* __restrict__ out) {
  __shared__ float red[256];
  int t = threadIdx.x;
  float sum = 0.0f;
  for (int r = t; r < B; r += 256) {
    uint32_t bk = 0u; float bd = 0.0f;
    float md = INFINITY;
#pragma unroll
    for (int ch = 0; ch < NCHUNK; ch++) {
      int p = r * NCHUNK + ch;
      uint32_t k = bestKey[p];
      if (k > bk) { bk = k; bd = bestDn[p]; }   // ascending chunk order: > keeps first
      float m = minDn[p];
      if (m < md) { md = m; }
    }
    float dn = (bk != 0u) ? bd : md;
    float sneg = sqrtf(dn);
    float x = 1e-4f + spos[r] - sneg;
    float sp = fmaxf(x, 0.0f) + log1pf(expf(-fabsf(x)));  // softplus = logaddexp(x,0)
    sum += sp;
  }
  red[t] = sum;
  __syncthreads();
#pragma unroll
  for (int s = 128; s; s >>= 1) {
    if (t < s) red[t] += red[t + s];
    __syncthreads();
  }
  if (t == 0) out[0] = red[0] * (1.0f / (float)B);
}

extern "C" void kernel_launch(void* const* d_in, const int* in_sizes, int n_in,
                              void* d_out, int out_size, void* d_ws, size_t ws_size,
                              hipStream_t stream) {
  (void)in_sizes; (void)n_in; (void)out_size; (void)ws_size;
  const float* Q = (const float*)d_in[0];
  const float* G = (const float*)d_in[1];
  float* out = (float*)d_out;
  float* ws = (float*)d_ws;

  float* nq = ws;                      // B
  float* ng = ws + B;                  // B
  float* pscore = ws + 2 * B;          // B
  float* spos = ws + 3 * B;            // B
  uint32_t* bestKey = (uint32_t*)(ws + 4 * B);            // B*NCHUNK
  uint32_t* bestC   = (uint32_t*)(ws + 4 * B + 1 * B * NCHUNK);
  float*    bestDn  = (float*)   (ws + 4 * B + 2 * B * NCHUNK);
  float*    minDn_  = (float*)   (ws + 4 * B + 3 * B * NCHUNK);
  uint32_t* minC_   = (uint32_t*)(ws + 4 * B + 4 * B * NCHUNK);

  // skey = jax.random.key(42) -> (0,42); split -> kp, kn
  uint32_t kp0, kp1, kn0, kn1;
#if RNG_PARTITIONABLE
  tf2x32(0u, 42u, 0u, 0u, kp0, kp1);
  tf2x32(0u, 42u, 0u, 1u, kn0, kn1);
#else
  {
    uint32_t a0, a1, b0, b1;
    tf2x32(0u, 42u, 0u, 2u, a0, a1);   // lane0: counts (0,2)
    tf2x32(0u, 42u, 1u, 3u, b0, b1);   // lane1: counts (1,3)
    kp0 = a0; kp1 = b0;                // concat(y0,y1).reshape(2,2)
    kn0 = a1; kn1 = b1;
  }
#endif

  hipLaunchKernelGGL(norms_k, dim3(2 * B / 4), dim3(256), 0, stream, Q, G, nq, ng);
  hipLaunchKernelGGL(pos_k, dim3(B / 8), dim3(256), 0, stream, Q, G, nq, ng, pscore, spos, kp0, kp1);
  hipLaunchKernelGGL(neg_k, dim3(NCHUNK, B / RT), dim3(256), 0, stream,
                     Q, G, nq, ng, pscore, kn0, kn1, bestKey, bestC, bestDn, minDn_, minC_);
  hipLaunchKernelGGL(fin_k, dim3(1), dim3(256), 0, stream,
                     spos, bestKey, bestC, bestDn, minDn_, minC_, out);
}

// Round 2
// 301.042 us; speedup vs baseline: 1.4828x; 1.4828x over previous
//
#include <hip/hip_runtime.h>
#include <hip/hip_fp16.h>
#include <stdint.h>
#include <math.h>

#define B 4096
#define D 512
#define NIMG_SHIFT 3

#define BM 128
#define BN 128
#define BK 64              // f16 elems per K-step per section
#define NKS (D / BK)       // 8
#define NCH (B / BN)       // 32 col chunks

typedef _Float16 f16x8 __attribute__((ext_vector_type(8)));
typedef float f32x4 __attribute__((ext_vector_type(4)));

#define LDSPTR(p) ((__attribute__((address_space(3))) void*)(p))
#define GLPTR(p)  ((const __attribute__((address_space(1))) void*)(p))

// -------- static device workspace (zero-init; fully rewritten every call) ----
__device__ __half   Q2d[(size_t)B * 1024];   // [r][0:512]=hi*2048, [512:1024]=lo
__device__ __half   G2d[(size_t)B * 1024];
__device__ float    nqd[B], ngd[B], psd[B], spd[B];
__device__ uint32_t bKeyd[B * NCH];
__device__ float    bDnd[B * NCH];
__device__ float    mDnd[B * NCH];

// ---------------- threefry2x32 ----------------
__host__ __device__ inline void tf2x32(uint32_t k0, uint32_t k1,
                                       uint32_t x0, uint32_t x1,
                                       uint32_t& y0, uint32_t& y1) {
  const uint32_t ks2 = k0 ^ k1 ^ 0x1BD11BDAu;
  uint32_t v0 = x0 + k0, v1 = x1 + k1;
#define RR(r) { v0 += v1; v1 = (v1 << (r)) | (v1 >> (32 - (r))); v1 ^= v0; }
  RR(13) RR(15) RR(26) RR(6)   v0 += k1;  v1 += ks2 + 1u;
  RR(17) RR(29) RR(16) RR(24)  v0 += ks2; v1 += k0 + 2u;
  RR(13) RR(15) RR(26) RR(6)   v0 += k0;  v1 += k1 + 3u;
  RR(17) RR(29) RR(16) RR(24)  v0 += k1;  v1 += ks2 + 4u;
  RR(13) RR(15) RR(26) RR(6)   v0 += ks2; v1 += k0 + 5u;
#undef RR
  y0 = v0; y1 = v1;
}

__device__ inline uint32_t draw_bits(uint32_t key0, uint32_t key1, uint32_t flat) {
  uint32_t y0, y1;
  tf2x32(key0, key1, 0u, flat, y0, y1);
  return y1;
}

__device__ inline float gumbel_from_bits(uint32_t bits) {
  float f = __uint_as_float((bits >> 9) | 0x3f800000u) - 1.0f;
  float u = (f == 0.0f) ? 1.17549435e-38f : f;
  return -logf(-logf(u));
}

// ---------------- Kernel 0: fp32 -> f16 hi/lo split (scaled by 2048) --------
__global__ __launch_bounds__(256) void cvt_k(const float* __restrict__ Q,
                                             const float* __restrict__ G) {
  int idx = blockIdx.x * 256 + threadIdx.x;      // 2 * B*D/4 total
  int isG = idx >= (B * D / 4);
  int e = isG ? idx - (B * D / 4) : idx;
  const float* src = isG ? G : Q;
  __half* dst = isG ? G2d : Q2d;
  float4 v = ((const float4*)src)[e];
  int r = e >> 7;               // 128 float4 per row
  int k4 = (e & 127) << 2;
  __half hh[4] __attribute__((aligned(8)));
  __half ll[4] __attribute__((aligned(8)));
  const float* pv = (const float*)&v;
#pragma unroll
  for (int j = 0; j < 4; j++) {
    float x = pv[j] * 2048.0f;
    __half h = __float2half(x);
    hh[j] = h;
    ll[j] = __float2half(x - __half2float(h));
  }
  *(uint2*)(dst + (size_t)r * 1024 + k4) = *(const uint2*)hh;
  *(uint2*)(dst + (size_t)r * 1024 + 512 + k4) = *(const uint2*)ll;
}

// ---------------- Kernel 1: row sum-of-squares ----------------
__global__ __launch_bounds__(256) void norms_k(const float* __restrict__ Q,
                                               const float* __restrict__ G) {
  int gtid = blockIdx.x * blockDim.x + threadIdx.x;
  int wave = gtid >> 6;
  int lane = gtid & 63;
  if (wave >= 2 * B) return;
  const float* src = (wave < B) ? Q : G;
  int row = (wave < B) ? wave : (wave - B);
  const float4* p = (const float4*)(src + (size_t)row * D);
  float s = 0.0f;
#pragma unroll
  for (int i = 0; i < 2; i++) {
    float4 v = p[lane + 64 * i];
    s += v.x * v.x + v.y * v.y + v.z * v.z + v.w * v.w;
  }
#pragma unroll
  for (int off = 32; off; off >>= 1) s += __shfl_xor(s, off, 64);
  if (lane == 0) { if (wave < B) nqd[row] = s; else ngd[row] = s; }
}

// ---------------- Kernel 2: positive categorical sampling ----------------
__global__ __launch_bounds__(256) void pos_k(const float* __restrict__ Q,
                                             const float* __restrict__ G,
                                             uint32_t kp0, uint32_t kp1) {
  __shared__ float Qs[8][D];
  __shared__ float Gs[8][D];
  __shared__ float dots[8][8];
  int t = threadIdx.x;
  int rbase = blockIdx.x * 8;
#pragma unroll
  for (int s = 0; s < 4; s++) {
    int idx = t + 256 * s;
    int rr = idx >> 7;
    int kk = idx & 127;
    ((float4*)&Qs[rr][0])[kk] = ((const float4*)(Q + (size_t)(rbase + rr) * D))[kk];
    ((float4*)&Gs[rr][0])[kk] = ((const float4*)(G + (size_t)(rbase + rr) * D))[kk];
  }
  __syncthreads();
  {
    int p = t >> 2;
    int part = t & 3;
    int i = p >> 3, j = p & 7;
    float s = 0.0f;
    int k0 = part * 128;
    for (int k = k0; k < k0 + 128; k++) s += Qs[i][k] * Gs[j][k];
    s += __shfl_xor(s, 1, 64);
    s += __shfl_xor(s, 2, 64);
    if (part == 0) dots[i][j] = s;
  }
  __syncthreads();
  if (t < 8) {
    int i = t;
    int r = rbase + i;
    float nqr = nqd[r];
    float best = -INFINITY;
    float bdp = 0.0f;
#pragma unroll
    for (int j = 0; j < 8; j++) {
      if (j == i) continue;
      int c = rbase + j;
      float dp = fmaxf(nqr + ngd[c] - 2.0f * dots[i][j], 1e-8f);
      uint32_t bits = draw_bits(kp0, kp1, (uint32_t)(r * B + c));
      float logit = logf(dp) + gumbel_from_bits(bits);
      if (logit > best) { best = logit; bdp = dp; }
    }
    psd[r] = bdp;
    spd[r] = sqrtf(bdp);
  }
}

// ---------------- Kernel 3: MFMA f16-split GEMM + neg-row reductions --------
__global__ __launch_bounds__(256) void neg_k(uint32_t kn0, uint32_t kn1) {
  __shared__ char lds[65536];   // Ah @0, Al @16K, Bh @32K, Bl @48K
  const int t = threadIdx.x;
  const int l = t & 63;
  const int w = t >> 6;
  const int wr = w >> 1, wc = w & 1;
  const int lane16 = l & 15, g16 = l >> 4;
  const int r0 = blockIdx.y * BM;
  const int c0 = blockIdx.x * BN;

  f32x4 acc[4][4];
#pragma unroll
  for (int mi = 0; mi < 4; mi++)
#pragma unroll
    for (int nj = 0; nj < 4; nj++) acc[mi][nj] = (f32x4){0.f, 0.f, 0.f, 0.f};

  const char* qbase = (const char*)Q2d + (size_t)r0 * 2048;
  const char* gbase = (const char*)G2d + (size_t)c0 * 2048;

#pragma unroll 1
  for (int ks = 0; ks < NKS; ks++) {
    __syncthreads();
    // stage 4 tiles of [128][64] f16 via global_load_lds, pre-swizzled source
#pragma unroll
    for (int s = 0; s < 4; s++) {
      const int li = (t + 256 * s) << 4;                 // linear dest byte
      const int aa = li ^ (((li >> 7) & 7) << 4);        // logical (row,kb)
      const int row = aa >> 7, kb = aa & 127;
      const char* qrow = qbase + (size_t)row * 2048 + ks * 128 + kb;
      const char* grow = gbase + (size_t)row * 2048 + ks * 128 + kb;
      __builtin_amdgcn_global_load_lds(GLPTR(qrow),        LDSPTR(lds + li),         16, 0, 0);
      __builtin_amdgcn_global_load_lds(GLPTR(qrow + 1024), LDSPTR(lds + 16384 + li), 16, 0, 0);
      __builtin_amdgcn_global_load_lds(GLPTR(grow),        LDSPTR(lds + 32768 + li), 16, 0, 0);
      __builtin_amdgcn_global_load_lds(GLPTR(grow + 1024), LDSPTR(lds + 49152 + li), 16, 0, 0);
    }
    __syncthreads();
    // compute: per kh half, 3-product split MFMA
#pragma unroll
    for (int kh = 0; kh < 2; kh++) {
      const int kbyte = kh * 64 + g16 * 16;
      f16x8 ah[4], al[4];
#pragma unroll
      for (int mi = 0; mi < 4; mi++) {
        const int row = wr * 64 + mi * 16 + lane16;
        const int a = row * 128 + kbyte;
        const int sw = a ^ (((a >> 7) & 7) << 4);
        ah[mi] = *(const f16x8*)(lds + sw);
        al[mi] = *(const f16x8*)(lds + 16384 + sw);
      }
#pragma unroll
      for (int nj = 0; nj < 4; nj++) {
        const int rowb = wc * 64 + nj * 16 + lane16;
        const int a = rowb * 128 + kbyte;
        const int sw = a ^ (((a >> 7) & 7) << 4);
        const f16x8 bh = *(const f16x8*)(lds + 32768 + sw);
        const f16x8 bl = *(const f16x8*)(lds + 49152 + sw);
#pragma unroll
        for (int mi = 0; mi < 4; mi++) {
          acc[mi][nj] = __builtin_amdgcn_mfma_f32_16x16x32_f16(ah[mi], bh, acc[mi][nj], 0, 0, 0);
          acc[mi][nj] = __builtin_amdgcn_mfma_f32_16x16x32_f16(al[mi], bh, acc[mi][nj], 0, 0, 0);
          acc[mi][nj] = __builtin_amdgcn_mfma_f32_16x16x32_f16(ah[mi], bl, acc[mi][nj], 0, 0, 0);
        }
      }
    }
  }
  __syncthreads();

  // epilogue partial arrays overlaid on LDS
  uint32_t* pKey = (uint32_t*)lds;
  uint32_t* pC   = pKey + 256;
  float*    pD   = (float*)(pC + 256);
  float*    pM   = pD + 256;
  uint32_t* pMC  = (uint32_t*)(pM + 256);

  // distance + per-row reductions. acc holds r*2^22; -2r = -acc * 2^-21
#pragma unroll
  for (int mi = 0; mi < 4; mi++) {
#pragma unroll
    for (int q = 0; q < 4; q++) {
      const int rr = wr * 64 + mi * 16 + g16 * 4 + q;
      const int r = r0 + rr;
      const float nqv = nqd[r];
      const float thr = psd[r] + 1e-4f;
      const int rg = r >> NIMG_SHIFT;
      uint32_t bKey = 0u, bC = 0xFFFFFFFFu, mC = 0xFFFFFFFFu;
      float bD = 0.0f, mD = INFINITY;
#pragma unroll
      for (int nj = 0; nj < 4; nj++) {
        const int c = c0 + wc * 64 + nj * 16 + lane16;
        const float dv = fmaxf(nqv + ngd[c] - acc[mi][nj][q] * 4.76837158203125e-07f, 1e-8f);
        const float dn = ((c >> NIMG_SHIFT) == rg) ? 1e25f : dv;
        if (dn < mD || (dn == mD && (uint32_t)c < mC)) { mD = dn; mC = (uint32_t)c; }
        if (dn < thr) {
          const uint32_t bits = draw_bits(kn0, kn1, (uint32_t)(r * B + c));
          const uint32_t key = (bits >> 9) + 1u;
          if (key > bKey || (key == bKey && (uint32_t)c < bC)) { bKey = key; bC = (uint32_t)c; bD = dn; }
        }
      }
#pragma unroll
      for (int off = 8; off >= 1; off >>= 1) {
        const uint32_t kO = __shfl_xor(bKey, off, 64);
        const uint32_t cO = __shfl_xor(bC, off, 64);
        const float dO = __shfl_xor(bD, off, 64);
        if (kO > bKey || (kO == bKey && cO < bC)) { bKey = kO; bC = cO; bD = dO; }
        const float mdO = __shfl_xor(mD, off, 64);
        const uint32_t mcO = __shfl_xor(mC, off, 64);
        if (mdO < mD || (mdO == mD && mcO < mC)) { mD = mdO; mC = mcO; }
      }
      if (lane16 == 0) {
        const int idx = wc * 128 + rr;
        pKey[idx] = bKey; pC[idx] = bC; pD[idx] = bD; pM[idx] = mD; pMC[idx] = mC;
      }
    }
  }
  __syncthreads();
  if (t < 128) {
    const int i0 = t, i1 = t + 128;
    const uint32_t k0 = pKey[i0], k1 = pKey[i1];
    const uint32_t c0v = pC[i0], c1v = pC[i1];
    const float d0 = pD[i0], d1 = pD[i1];
    uint32_t bk; float bd;
    if (k1 > k0 || (k1 == k0 && k1 != 0u && c1v < c0v)) { bk = k1; bd = d1; }
    else { bk = k0; bd = d0; }
    const float m0 = pM[i0], m1 = pM[i1];
    const uint32_t mc0 = pMC[i0], mc1 = pMC[i1];
    const float md = (m1 < m0 || (m1 == m0 && mc1 < mc0)) ? m1 : m0;
    const int p = (r0 + t) * NCH + blockIdx.x;
    bKeyd[p] = bk; bDnd[p] = bd; mDnd[p] = md;
  }
}

// ---------------- Kernel 4: combine chunks, softplus, mean ----------------
__global__ __launch_bounds__(256) void fin_k(float* __restrict__ out) {
  __shared__ float red[256];
  int t = threadIdx.x;
  float sum = 0.0f;
  for (int r = t; r < B; r += 256) {
    uint32_t bk = 0u; float bd = 0.0f;
    float md = INFINITY;
#pragma unroll
    for (int ch = 0; ch < NCH; ch++) {
      int p = r * NCH + ch;
      uint32_t k = bKeyd[p];
      if (k > bk) { bk = k; bd = bDnd[p]; }
      float m = mDnd[p];
      if (m < md) md = m;
    }
    float dn = (bk != 0u) ? bd : md;
    float x = 1e-4f + spd[r] - sqrtf(dn);
    sum += fmaxf(x, 0.0f) + log1pf(expf(-fabsf(x)));
  }
  red[t] = sum;
  __syncthreads();
#pragma unroll
  for (int s = 128; s; s >>= 1) {
    if (t < s) red[t] += red[t + s];
    __syncthreads();
  }
  if (t == 0) out[0] = red[0] * (1.0f / (float)B);
}

extern "C" void kernel_launch(void* const* d_in, const int* in_sizes, int n_in,
                              void* d_out, int out_size, void* d_ws, size_t ws_size,
                              hipStream_t stream) {
  (void)in_sizes; (void)n_in; (void)out_size; (void)d_ws; (void)ws_size;
  const float* Q = (const float*)d_in[0];
  const float* G = (const float*)d_in[1];
  float* out = (float*)d_out;

  uint32_t kp0, kp1, kn0, kn1;
  tf2x32(0u, 42u, 0u, 0u, kp0, kp1);
  tf2x32(0u, 42u, 0u, 1u, kn0, kn1);

  hipLaunchKernelGGL(cvt_k, dim3(2 * B * D / 4 / 256), dim3(256), 0, stream, Q, G);
  hipLaunchKernelGGL(norms_k, dim3(2 * B / 4), dim3(256), 0, stream, Q, G);
  hipLaunchKernelGGL(pos_k, dim3(B / 8), dim3(256), 0, stream, Q, G, kp0, kp1);
  hipLaunchKernelGGL(neg_k, dim3(NCH, B / BM), dim3(256), 0, stream, kn0, kn1);
  hipLaunchKernelGGL(fin_k, dim3(1), dim3(256), 0, stream, out);
}

// Round 3
// 156.653 us; speedup vs baseline: 2.8494x; 1.9217x over previous
//
#include <hip/hip_runtime.h>
#include <hip/hip_fp16.h>
#include <stdint.h>
#include <math.h>

#define B 4096
#define D 512
#define NIMG_SHIFT 3

#define BM 128
#define BN 128
#define BK 64              // f16 elems per K-step per section
#define NKS (D / BK)       // 8
#define NCH (B / BN)       // 32 col chunks

typedef _Float16 f16x8 __attribute__((ext_vector_type(8)));
typedef float f32x4 __attribute__((ext_vector_type(4)));

#define LDSPTR(p) ((__attribute__((address_space(3))) void*)(p))
#define GLPTR(p)  ((const __attribute__((address_space(1))) void*)(p))

// -------- static device workspace (fully rewritten every call) ----
__device__ __half   Q2d[(size_t)B * 1024];   // [r][0:512]=hi*2048, [512:1024]=lo
__device__ __half   G2d[(size_t)B * 1024];
__device__ float    nqd[B], ngd[B], psd[B], spd[B];
__device__ uint32_t bKeyd[B * NCH];
__device__ float    bDnd[B * NCH];
__device__ float    mDnd[B * NCH];
__device__ float    partd[B / 8];

// ---------------- threefry2x32 ----------------
__host__ __device__ inline void tf2x32(uint32_t k0, uint32_t k1,
                                       uint32_t x0, uint32_t x1,
                                       uint32_t& y0, uint32_t& y1) {
  const uint32_t ks2 = k0 ^ k1 ^ 0x1BD11BDAu;
  uint32_t v0 = x0 + k0, v1 = x1 + k1;
#define RR(r) { v0 += v1; v1 = (v1 << (r)) | (v1 >> (32 - (r))); v1 ^= v0; }
  RR(13) RR(15) RR(26) RR(6)   v0 += k1;  v1 += ks2 + 1u;
  RR(17) RR(29) RR(16) RR(24)  v0 += ks2; v1 += k0 + 2u;
  RR(13) RR(15) RR(26) RR(6)   v0 += k0;  v1 += k1 + 3u;
  RR(17) RR(29) RR(16) RR(24)  v0 += k1;  v1 += ks2 + 4u;
  RR(13) RR(15) RR(26) RR(6)   v0 += ks2; v1 += k0 + 5u;
#undef RR
  y0 = v0; y1 = v1;
}

__device__ inline uint32_t draw_bits(uint32_t key0, uint32_t key1, uint32_t flat) {
  uint32_t y0, y1;
  tf2x32(key0, key1, 0u, flat, y0, y1);
  return y1;
}

__device__ inline float gumbel_from_bits(uint32_t bits) {
  float f = __uint_as_float((bits >> 9) | 0x3f800000u) - 1.0f;
  float u = (f == 0.0f) ? 1.17549435e-38f : f;
  return -logf(-logf(u));
}

// ---------------- Kernel 0: fp32 -> f16 hi/lo split (scaled by 2048) --------
__global__ __launch_bounds__(256) void cvt_k(const float* __restrict__ Q,
                                             const float* __restrict__ G) {
  int idx = blockIdx.x * 256 + threadIdx.x;      // 2 * B*D/4 total
  int isG = idx >= (B * D / 4);
  int e = isG ? idx - (B * D / 4) : idx;
  const float* src = isG ? G : Q;
  __half* dst = isG ? G2d : Q2d;
  float4 v = ((const float4*)src)[e];
  int r = e >> 7;               // 128 float4 per row
  int k4 = (e & 127) << 2;
  __half hh[4] __attribute__((aligned(8)));
  __half ll[4] __attribute__((aligned(8)));
  const float* pv = (const float*)&v;
#pragma unroll
  for (int j = 0; j < 4; j++) {
    float x = pv[j] * 2048.0f;
    __half h = __float2half(x);
    hh[j] = h;
    ll[j] = __float2half(x - __half2float(h));
  }
  *(uint2*)(dst + (size_t)r * 1024 + k4) = *(const uint2*)hh;
  *(uint2*)(dst + (size_t)r * 1024 + 512 + k4) = *(const uint2*)ll;
}

// ---------------- Kernel 1: row sum-of-squares ----------------
__global__ __launch_bounds__(256) void norms_k(const float* __restrict__ Q,
                                               const float* __restrict__ G) {
  int gtid = blockIdx.x * blockDim.x + threadIdx.x;
  int wave = gtid >> 6;
  int lane = gtid & 63;
  if (wave >= 2 * B) return;
  const float* src = (wave < B) ? Q : G;
  int row = (wave < B) ? wave : (wave - B);
  const float4* p = (const float4*)(src + (size_t)row * D);
  float s = 0.0f;
#pragma unroll
  for (int i = 0; i < 2; i++) {
    float4 v = p[lane + 64 * i];
    s += v.x * v.x + v.y * v.y + v.z * v.z + v.w * v.w;
  }
#pragma unroll
  for (int off = 32; off; off >>= 1) s += __shfl_xor(s, off, 64);
  if (lane == 0) { if (wave < B) nqd[row] = s; else ngd[row] = s; }
}

// ---------------- Kernel 2: positive categorical sampling ----------------
__global__ __launch_bounds__(256) void pos_k(const float* __restrict__ Q,
                                             const float* __restrict__ G,
                                             uint32_t kp0, uint32_t kp1) {
  __shared__ float Qs[8][D];
  __shared__ float Gs[8][D];
  __shared__ float dots[8][8];
  int t = threadIdx.x;
  int rbase = blockIdx.x * 8;
#pragma unroll
  for (int s = 0; s < 4; s++) {
    int idx = t + 256 * s;
    int rr = idx >> 7;
    int kk = idx & 127;
    ((float4*)&Qs[rr][0])[kk] = ((const float4*)(Q + (size_t)(rbase + rr) * D))[kk];
    ((float4*)&Gs[rr][0])[kk] = ((const float4*)(G + (size_t)(rbase + rr) * D))[kk];
  }
  __syncthreads();
  {
    int p = t >> 2;
    int part = t & 3;
    int i = p >> 3, j = p & 7;
    float s = 0.0f;
    int k0 = part * 128;
    for (int k = k0; k < k0 + 128; k++) s += Qs[i][k] * Gs[j][k];
    s += __shfl_xor(s, 1, 64);
    s += __shfl_xor(s, 2, 64);
    if (part == 0) dots[i][j] = s;
  }
  __syncthreads();
  if (t < 8) {
    int i = t;
    int r = rbase + i;
    float nqr = nqd[r];
    float best = -INFINITY;
    float bdp = 0.0f;
#pragma unroll
    for (int j = 0; j < 8; j++) {
      if (j == i) continue;
      int c = rbase + j;
      float dp = fmaxf(nqr + ngd[c] - 2.0f * dots[i][j], 1e-8f);
      uint32_t bits = draw_bits(kp0, kp1, (uint32_t)(r * B + c));
      float logit = logf(dp) + gumbel_from_bits(bits);
      if (logit > best) { best = logit; bdp = dp; }
    }
    psd[r] = bdp;
    spd[r] = sqrtf(bdp);
  }
}

// ---------------- Kernel 3: MFMA f16-split GEMM + neg-row reductions --------
__global__ __launch_bounds__(256) void neg_k(uint32_t kn0, uint32_t kn1) {
  __shared__ char lds[65536];   // Ah @0, Al @16K, Bh @32K, Bl @48K
  const int t = threadIdx.x;
  const int l = t & 63;
  const int w = t >> 6;
  const int wr = w >> 1, wc = w & 1;
  const int lane16 = l & 15, g16 = l >> 4;
  const int r0 = blockIdx.y * BM;
  const int c0 = blockIdx.x * BN;

  f32x4 acc[4][4];
#pragma unroll
  for (int mi = 0; mi < 4; mi++)
#pragma unroll
    for (int nj = 0; nj < 4; nj++) acc[mi][nj] = (f32x4){0.f, 0.f, 0.f, 0.f};

  const char* qbase = (const char*)Q2d + (size_t)r0 * 2048;
  const char* gbase = (const char*)G2d + (size_t)c0 * 2048;

#pragma unroll 1
  for (int ks = 0; ks < NKS; ks++) {
    __syncthreads();
    // stage 4 tiles of [128][64] f16 via global_load_lds, pre-swizzled source
#pragma unroll
    for (int s = 0; s < 4; s++) {
      const int li = (t + 256 * s) << 4;                 // linear dest byte
      const int aa = li ^ (((li >> 7) & 7) << 4);        // logical (row,kb)
      const int row = aa >> 7, kb = aa & 127;
      const char* qrow = qbase + (size_t)row * 2048 + ks * 128 + kb;
      const char* grow = gbase + (size_t)row * 2048 + ks * 128 + kb;
      __builtin_amdgcn_global_load_lds(GLPTR(qrow),        LDSPTR(lds + li),         16, 0, 0);
      __builtin_amdgcn_global_load_lds(GLPTR(qrow + 1024), LDSPTR(lds + 16384 + li), 16, 0, 0);
      __builtin_amdgcn_global_load_lds(GLPTR(grow),        LDSPTR(lds + 32768 + li), 16, 0, 0);
      __builtin_amdgcn_global_load_lds(GLPTR(grow + 1024), LDSPTR(lds + 49152 + li), 16, 0, 0);
    }
    __syncthreads();
    // compute: per kh half, 3-product split MFMA
#pragma unroll
    for (int kh = 0; kh < 2; kh++) {
      const int kbyte = kh * 64 + g16 * 16;
      f16x8 ah[4], al[4];
#pragma unroll
      for (int mi = 0; mi < 4; mi++) {
        const int row = wr * 64 + mi * 16 + lane16;
        const int a = row * 128 + kbyte;
        const int sw = a ^ (((a >> 7) & 7) << 4);
        ah[mi] = *(const f16x8*)(lds + sw);
        al[mi] = *(const f16x8*)(lds + 16384 + sw);
      }
#pragma unroll
      for (int nj = 0; nj < 4; nj++) {
        const int rowb = wc * 64 + nj * 16 + lane16;
        const int a = rowb * 128 + kbyte;
        const int sw = a ^ (((a >> 7) & 7) << 4);
        const f16x8 bh = *(const f16x8*)(lds + 32768 + sw);
        const f16x8 bl = *(const f16x8*)(lds + 49152 + sw);
#pragma unroll
        for (int mi = 0; mi < 4; mi++) {
          acc[mi][nj] = __builtin_amdgcn_mfma_f32_16x16x32_f16(ah[mi], bh, acc[mi][nj], 0, 0, 0);
          acc[mi][nj] = __builtin_amdgcn_mfma_f32_16x16x32_f16(al[mi], bh, acc[mi][nj], 0, 0, 0);
          acc[mi][nj] = __builtin_amdgcn_mfma_f32_16x16x32_f16(ah[mi], bl, acc[mi][nj], 0, 0, 0);
        }
      }
    }
  }
  __syncthreads();

  // epilogue partial arrays overlaid on LDS
  uint32_t* pKey = (uint32_t*)lds;
  uint32_t* pC   = pKey + 256;
  float*    pD   = (float*)(pC + 256);
  float*    pM   = pD + 256;
  uint32_t* pMC  = (uint32_t*)(pM + 256);

  // distance + per-row reductions. acc holds r*2^22; -2r = -acc * 2^-21
#pragma unroll
  for (int mi = 0; mi < 4; mi++) {
#pragma unroll
    for (int q = 0; q < 4; q++) {
      const int rr = wr * 64 + mi * 16 + g16 * 4 + q;
      const int r = r0 + rr;
      const float nqv = nqd[r];
      const float thr = psd[r] + 1e-4f;
      const int rg = r >> NIMG_SHIFT;
      uint32_t bKey = 0u, bC = 0xFFFFFFFFu, mC = 0xFFFFFFFFu;
      float bD = 0.0f, mD = INFINITY;
#pragma unroll
      for (int nj = 0; nj < 4; nj++) {
        const int c = c0 + wc * 64 + nj * 16 + lane16;
        const float dv = fmaxf(nqv + ngd[c] - acc[mi][nj][q] * 4.76837158203125e-07f, 1e-8f);
        const float dn = ((c >> NIMG_SHIFT) == rg) ? 1e25f : dv;
        if (dn < mD || (dn == mD && (uint32_t)c < mC)) { mD = dn; mC = (uint32_t)c; }
        if (dn < thr) {
          const uint32_t bits = draw_bits(kn0, kn1, (uint32_t)(r * B + c));
          const uint32_t key = (bits >> 9) + 1u;
          if (key > bKey || (key == bKey && (uint32_t)c < bC)) { bKey = key; bC = (uint32_t)c; bD = dn; }
        }
      }
#pragma unroll
      for (int off = 8; off >= 1; off >>= 1) {
        const uint32_t kO = __shfl_xor(bKey, off, 64);
        const uint32_t cO = __shfl_xor(bC, off, 64);
        const float dO = __shfl_xor(bD, off, 64);
        if (kO > bKey || (kO == bKey && cO < bC)) { bKey = kO; bC = cO; bD = dO; }
        const float mdO = __shfl_xor(mD, off, 64);
        const uint32_t mcO = __shfl_xor(mC, off, 64);
        if (mdO < mD || (mdO == mD && mcO < mC)) { mD = mdO; mC = mcO; }
      }
      if (lane16 == 0) {
        const int idx = wc * 128 + rr;
        pKey[idx] = bKey; pC[idx] = bC; pD[idx] = bD; pM[idx] = mD; pMC[idx] = mC;
      }
    }
  }
  __syncthreads();
  if (t < 128) {
    const int i0 = t, i1 = t + 128;
    const uint32_t k0 = pKey[i0], k1 = pKey[i1];
    const uint32_t c0v = pC[i0], c1v = pC[i1];
    const float d0 = pD[i0], d1 = pD[i1];
    uint32_t bk; float bd;
    if (k1 > k0 || (k1 == k0 && k1 != 0u && c1v < c0v)) { bk = k1; bd = d1; }
    else { bk = k0; bd = d0; }
    const float m0 = pM[i0], m1 = pM[i1];
    const uint32_t mc0 = pMC[i0], mc1 = pMC[i1];
    const float md = (m1 < m0 || (m1 == m0 && mc1 < mc0)) ? m1 : m0;
    const int p = (r0 + t) * NCH + blockIdx.x;
    bKeyd[p] = bk; bDnd[p] = bd; mDnd[p] = md;
  }
}

// ---------------- Kernel 4a: per-row chunk combine + softplus, block partial --
__global__ __launch_bounds__(256) void fin1_k() {
  __shared__ float red[8];
  const int t = threadIdx.x;
  const int lrow = t >> 5;              // 0..7 rows per block
  const int ch = t & 31;                // chunk index
  const int r = blockIdx.x * 8 + lrow;
  const int p = r * NCH + ch;
  uint32_t bk = bKeyd[p];
  uint32_t bch = (uint32_t)ch;
  float bd = bDnd[p];
  float md = mDnd[p];
  uint32_t mch = (uint32_t)ch;
  // reduce over 32 chunk-lanes: (key desc, chunk asc) / (min asc, chunk asc)
#pragma unroll
  for (int off = 16; off >= 1; off >>= 1) {
    const uint32_t kO = __shfl_xor(bk, off, 64);
    const uint32_t cO = __shfl_xor(bch, off, 64);
    const float dO = __shfl_xor(bd, off, 64);
    if (kO > bk || (kO == bk && cO < bch)) { bk = kO; bch = cO; bd = dO; }
    const float mO = __shfl_xor(md, off, 64);
    const uint32_t mcO = __shfl_xor(mch, off, 64);
    if (mO < md || (mO == md && mcO < mch)) { md = mO; mch = mcO; }
  }
  if (ch == 0) {
    const float dn = (bk != 0u) ? bd : md;
    const float x = 1e-4f + spd[r] - sqrtf(dn);
    red[lrow] = fmaxf(x, 0.0f) + log1pf(expf(-fabsf(x)));
  }
  __syncthreads();
  if (t == 0) {
    float s = 0.0f;
#pragma unroll
    for (int i = 0; i < 8; i++) s += red[i];
    partd[blockIdx.x] = s;
  }
}

// ---------------- Kernel 4b: sum 512 partials, mean ----------------
__global__ __launch_bounds__(256) void fin2_k(float* __restrict__ out) {
  __shared__ float red[256];
  const int t = threadIdx.x;
  red[t] = partd[t] + partd[t + 256];
  __syncthreads();
#pragma unroll
  for (int s = 128; s; s >>= 1) {
    if (t < s) red[t] += red[t + s];
    __syncthreads();
  }
  if (t == 0) out[0] = red[0] * (1.0f / (float)B);
}

extern "C" void kernel_launch(void* const* d_in, const int* in_sizes, int n_in,
                              void* d_out, int out_size, void* d_ws, size_t ws_size,
                              hipStream_t stream) {
  (void)in_sizes; (void)n_in; (void)out_size; (void)d_ws; (void)ws_size;
  const float* Q = (const float*)d_in[0];
  const float* G = (const float*)d_in[1];
  float* out = (float*)d_out;

  uint32_t kp0, kp1, kn0, kn1;
  tf2x32(0u, 42u, 0u, 0u, kp0, kp1);
  tf2x32(0u, 42u, 0u, 1u, kn0, kn1);

  hipLaunchKernelGGL(cvt_k, dim3(2 * B * D / 4 / 256), dim3(256), 0, stream, Q, G);
  hipLaunchKernelGGL(norms_k, dim3(2 * B / 4), dim3(256), 0, stream, Q, G);
  hipLaunchKernelGGL(pos_k, dim3(B / 8), dim3(256), 0, stream, Q, G, kp0, kp1);
  hipLaunchKernelGGL(neg_k, dim3(NCH, B / BM), dim3(256), 0, stream, kn0, kn1);
  hipLaunchKernelGGL(fin1_k, dim3(B / 8), dim3(256), 0, stream);
  hipLaunchKernelGGL(fin2_k, dim3(1), dim3(256), 0, stream, out);
}